// Round 8
// baseline (304.213 us; speedup 1.0000x reference)
//
#include <hip/hip_runtime.h>
#include <cstdint>

#define Bsz 32
#define Dd 2048
#define Ff 512
#define TP 16            // padded term stride (alignment of coeff/q rows)
#define TU 12            // Taylor terms USED (t=0..11): omitted z^12/12! <= 1.1e-5
#define NC 32            // d-chunks in k_mom (1024 blocks = 4/CU)
#define DC (Dd / NC)     // 64 rows per chunk

// ---------------------------------------------------------------------------
// P[d,j] = exp(scal_d*s_j - A_j)/Z_d, A_j = sum_k|s_j-s_k|, scal_d = 2047-2d,
// Z_d = sum_j exp(scal_d*s_j - A_j).
// s in [0,1e-3) -> |scal_d*s_j| <= 2.047; exp(z) = sum_t z^t/t!, 12 terms.
// With u_d = scal_d/2048 (|u|<1) and v_j = 2048*s_j (0<=v<2.05):
//   out[b,j,f] = e^{-A_j} * sum_t (v_j^t/t!) * Y[b,t,f]
//   Y[b,t,f]   = sum_d (u_d^t * w_d) * x[b,d,f],  w_d = 1/Z_d
// Round-7 post-mortem: k_mom/k_out are LDS-broadcast-pipe bound (~20 us each:
// 4096 ds_read_b128/CU x 12cyc), NOT VALU-bound (rank cut 16->13 moved
// nothing). This round: TU=12 (3xb128 rows), k_mom 2-row float4 (LDS ops/wave
// 256->96) + end half-reduction, k_out float4 jg-split (LDS 256->96, 16B
// stores). Pipeline structure (NC=32 + Yp + k_red) unchanged -- proven best.
// ---------------------------------------------------------------------------

// K1: A_j = sum_k |s_j - s_k|; also q[j][t] = e^{-A_j} * v_j^t / t!  (padded 16)
__global__ __launch_bounds__(256) void k_prep(const float* __restrict__ s,
                                              float* __restrict__ abs_sum,
                                              float* __restrict__ q) {
  __shared__ float sk[256];
  int t = threadIdx.x;
  int j = blockIdx.x * 256 + t;
  float sj = s[j];
  float acc = 0.f;
  for (int c = 0; c < Dd; c += 256) {
    __syncthreads();
    sk[t] = s[c + t];
    __syncthreads();
#pragma unroll 16
    for (int k = 0; k < 256; k += 4) {
      float4 sv = *(const float4*)&sk[k];   // broadcast b128 reads
      acc += fabsf(sj - sv.x) + fabsf(sj - sv.y) + fabsf(sj - sv.z) + fabsf(sj - sv.w);
    }
  }
  abs_sum[j] = acc;
  float v = 2048.0f * sj;
  float p = __expf(-acc);
  float4 q0, q1, q2, q3;
  q0.x = p;                              // t=0
  p *= v;                q0.y = p;       // t=1
  p *= v * 0.5f;         q0.z = p;       // t=2
  p *= v * (1.f / 3.f);  q0.w = p;       // t=3
  p *= v * 0.25f;        q1.x = p;       // t=4
  p *= v * 0.2f;         q1.y = p;       // t=5
  p *= v * (1.f / 6.f);  q1.z = p;       // t=6
  p *= v * (1.f / 7.f);  q1.w = p;       // t=7
  p *= v * 0.125f;       q2.x = p;       // t=8
  p *= v * (1.f / 9.f);  q2.y = p;       // t=9
  p *= v * 0.1f;         q2.z = p;       // t=10
  p *= v * (1.f / 11.f); q2.w = p;       // t=11
  q3.x = 0.f; q3.y = 0.f; q3.z = 0.f; q3.w = 0.f;   // padding t=12..15
  float4* qv = (float4*)&q[(size_t)j * TP];
  qv[0] = q0; qv[1] = q1; qv[2] = q2; qv[3] = q3;
}

// K2: per d: Z_d (wave reduction), then coeff[d][t] = u_d^t / Z_d (padded 16).
__global__ __launch_bounds__(256) void k_wd(const float* __restrict__ s,
                                            const float* __restrict__ abs_sum,
                                            float* __restrict__ coeff) {
  int w = threadIdx.x >> 6, l = threadIdx.x & 63;
  int d = blockIdx.x * 4 + w;
  float scal = 2047.0f - 2.0f * (float)d;
  float sum = 0.f;
#pragma unroll
  for (int it = 0; it < 32; ++it) {
    int j = it * 64 + l;
    sum += __expf(fmaf(scal, s[j], -abs_sum[j]));
  }
#pragma unroll
  for (int off = 32; off > 0; off >>= 1) sum += __shfl_xor(sum, off, 64);
  float wd = 1.0f / sum;
  float u = scal * (1.0f / 2048.0f);
  if (l < TP) {
    float p = (l < TU) ? wd : 0.f;
    for (int k = 0; k < l; ++k) p *= u;   // tiny divergent loop, <=15 iters
    coeff[(size_t)d * TP + l] = p;
  }
}

// K3: moment partials. Yp[ch][b][t][f] = sum_{d in chunk} coeff[d][t]*x[b][d][f].
// One block = one (b, chunk). Thread t: f = (t&127)*4 (float4), row parity
// t>>7 -- two rows in flight per iteration (4 KB coalesced per block-iter).
// LDS broadcasts: 3 x b128 per 2 rows (was 4 per row). End: half-reduction
// in LDS ([tt][fi] layout, conflict-free), half-0 threads store float4.
__global__ __launch_bounds__(256) void k_mom(const float* __restrict__ x,
                                             const float* __restrict__ coeff,
                                             float* __restrict__ Yp) {
  __shared__ float cf[DC * TP];          // 4 KB
  __shared__ float red[TU][128 * 4];     // 24 KB
  int t = threadIdx.x;
  int b = blockIdx.x;
  int ch = blockIdx.y;
  *(float4*)&cf[t * 4] = *(const float4*)&coeff[(size_t)ch * DC * TP + t * 4];
  __syncthreads();

  int fi = t & 127;      // f = fi*4
  int half = t >> 7;     // row parity

  const float* xb = x + ((size_t)b * Dd + (size_t)ch * DC) * Ff + fi * 4;
  float4 acc[TU];
#pragma unroll
  for (int tt = 0; tt < TU; ++tt) acc[tt] = make_float4(0.f, 0.f, 0.f, 0.f);

#pragma unroll 4
  for (int i = 0; i < DC; i += 2) {
    int d = i + half;
    float4 xv = *(const float4*)&xb[(size_t)d * Ff];
    const float4* cp = (const float4*)&cf[d * TP];  // wave-uniform: broadcast
    float cfr[TU];
    *(float4*)&cfr[0] = cp[0];
    *(float4*)&cfr[4] = cp[1];
    *(float4*)&cfr[8] = cp[2];
#pragma unroll
    for (int tt = 0; tt < TU; ++tt) {
      acc[tt].x = fmaf(cfr[tt], xv.x, acc[tt].x);
      acc[tt].y = fmaf(cfr[tt], xv.y, acc[tt].y);
      acc[tt].z = fmaf(cfr[tt], xv.z, acc[tt].z);
      acc[tt].w = fmaf(cfr[tt], xv.w, acc[tt].w);
    }
  }

  if (half) {
#pragma unroll
    for (int tt = 0; tt < TU; ++tt)
      *(float4*)&red[tt][fi * 4] = acc[tt];
  }
  __syncthreads();
  if (!half) {
    float* yp = Yp + ((size_t)(ch * Bsz + b) * TU) * Ff + fi * 4;
#pragma unroll
    for (int tt = 0; tt < TU; ++tt) {
      float4 r = *(const float4*)&red[tt][fi * 4];
      acc[tt].x += r.x; acc[tt].y += r.y; acc[tt].z += r.z; acc[tt].w += r.w;
      *(float4*)&yp[(size_t)tt * Ff] = acc[tt];
    }
  }
}

// K3b: reduce partials over chunks: Y[b][t][f] = sum_ch Yp[ch][b][t][f].
// Yp slabs are fresh in L2/L3 -> mostly cache reads.
__global__ __launch_bounds__(256) void k_red(const float* __restrict__ Yp,
                                             float* __restrict__ Y) {
  int i = (blockIdx.x * 256 + threadIdx.x) * 4;  // over B*TU*F = 196608 floats
  float4 a = make_float4(0.f, 0.f, 0.f, 0.f);
#pragma unroll
  for (int c = 0; c < NC; ++c) {
    float4 v = *(const float4*)&Yp[(size_t)c * (Bsz * TU * Ff) + i];
    a.x += v.x; a.y += v.y; a.z += v.z; a.w += v.w;
  }
  *(float4*)&Y[i] = a;
}

// K4: out[b][j][f] = sum_t q[j][t] * Y[b][t][f].
// One block = (b, 64-row j-tile); thread t: f = (t&127)*4, jg = t>>7 (2-way
// j-parallelism, 32 iters). Y slice in registers (float4), q in LDS
// (3 x b128 broadcast per j); float4 stores (16 B/lane).
__global__ __launch_bounds__(256) void k_out(const float* __restrict__ Y,
                                             const float* __restrict__ q,
                                             float* __restrict__ out) {
  __shared__ float qs[64 * TP];  // 4 KB
  int t = threadIdx.x;
  int b = blockIdx.x;
  int j0 = blockIdx.y * 64;
  *(float4*)&qs[t * 4] = *(const float4*)&q[(size_t)j0 * TP + t * 4];
  __syncthreads();

  int fi = t & 127;      // f = fi*4
  int jg = t >> 7;       // 0..1

  const float* yb = Y + (size_t)b * TU * Ff + fi * 4;
  float4 y[TU];
#pragma unroll
  for (int tt = 0; tt < TU; ++tt) y[tt] = *(const float4*)&yb[(size_t)tt * Ff];

  float* ob = out + ((size_t)b * Dd + j0 + jg * 32) * Ff + fi * 4;
  for (int j = 0; j < 32; ++j) {
    const float4* qp = (const float4*)&qs[(jg * 32 + j) * TP];  // broadcast
    float qr[TU];
    *(float4*)&qr[0] = qp[0];
    *(float4*)&qr[4] = qp[1];
    *(float4*)&qr[8] = qp[2];
    // two-way split to halve the fma dependency chain
    float4 o0 = make_float4(0.f, 0.f, 0.f, 0.f);
    float4 o1 = make_float4(0.f, 0.f, 0.f, 0.f);
#pragma unroll
    for (int tt = 0; tt < TU; tt += 2) {
      o0.x = fmaf(qr[tt], y[tt].x, o0.x);
      o0.y = fmaf(qr[tt], y[tt].y, o0.y);
      o0.z = fmaf(qr[tt], y[tt].z, o0.z);
      o0.w = fmaf(qr[tt], y[tt].w, o0.w);
      o1.x = fmaf(qr[tt + 1], y[tt + 1].x, o1.x);
      o1.y = fmaf(qr[tt + 1], y[tt + 1].y, o1.y);
      o1.z = fmaf(qr[tt + 1], y[tt + 1].z, o1.z);
      o1.w = fmaf(qr[tt + 1], y[tt + 1].w, o1.w);
    }
    float4 o = make_float4(o0.x + o1.x, o0.y + o1.y, o0.z + o1.z, o0.w + o1.w);
    *(float4*)&ob[(size_t)j * Ff] = o;
  }
}

extern "C" void kernel_launch(void* const* d_in, const int* in_sizes, int n_in,
                              void* d_out, int out_size, void* d_ws, size_t ws_size,
                              hipStream_t stream) {
  const float* x = (const float*)d_in[0];
  const float* s = (const float*)d_in[1];
  float* out = (float*)d_out;

  char* ws = (char*)d_ws;
  float* abs_sum = (float*)ws;                            // 8 KB
  float* q = (float*)(ws + 8192);                         // 128 KB
  float* coeff = (float*)(ws + 8192 + 131072);            // 128 KB
  float* Y = (float*)(ws + 270336);                       // 768 KB (32*12*512*4)
  float* Yp = (float*)(ws + 270336 + 786432);             // 25.2 MB

  k_prep<<<Dd / 256, 256, 0, stream>>>(s, abs_sum, q);
  k_wd<<<Dd / 4, 256, 0, stream>>>(s, abs_sum, coeff);
  k_mom<<<dim3(Bsz, NC), 256, 0, stream>>>(x, coeff, Yp);
  k_red<<<(Bsz * TU * Ff) / (256 * 4), 256, 0, stream>>>(Yp, Y);
  k_out<<<dim3(Bsz, Dd / 64), 256, 0, stream>>>(Y, q, out);
}

// Round 9
// 283.377 us; speedup vs baseline: 1.0735x; 1.0735x over previous
//
#include <hip/hip_runtime.h>
#include <cstdint>

#define Bsz 32
#define Dd 2048
#define Ff 512
#define TP 16            // padded term stride (alignment of coeff/q rows)
#define TU 12            // Taylor terms USED (t=0..11): omitted z^12/12! <= 1.1e-5
#define NC 32            // d-chunks in k_mom (1024 blocks = 4/CU: proven cfg)
#define DC (Dd / NC)     // 64 rows per chunk

// ---------------------------------------------------------------------------
// P[d,j] = exp(scal_d*s_j - A_j)/Z_d, A_j = sum_k|s_j-s_k|, scal_d = 2047-2d,
// Z_d = sum_j exp(scal_d*s_j - A_j).
// s in [0,1e-3) -> |scal_d*s_j| <= 2.047; exp(z) = sum_t z^t/t!, 12 terms.
// With u_d = scal_d/2048 (|u|<1) and v_j = 2048*s_j (0<=v<2.05):
//   out[b,j,f] = e^{-A_j} * sum_t (v_j^t/t!) * Y[b,t,f]
//   Y[b,t,f]   = sum_d (u_d^t * w_d) * x[b,d,f],  w_d = 1/Z_d
// STRUCTURE IS THE r1/r7 PROVEN ONE. Session evidence: three k_mom/k_out
// restructures (NC=16, global-coeff, float4+LDS-red) all regressed to
// ~305; the simple float2 pipeline = ~285. This round is r7 verbatim with
// TU 13->12: coeff/q rows are exactly 3xb128 (one LDS op fewer per row),
// 8% fewer fma, 8% smaller Yp. Both big kernels are VALU-issue-bound just
// above their ~22 us memory floors, so cost scales with TU.
// ---------------------------------------------------------------------------

// K1: A_j = sum_k |s_j - s_k|; also q[j][t] = e^{-A_j} * v_j^t / t!  (padded 16)
__global__ __launch_bounds__(256) void k_prep(const float* __restrict__ s,
                                              float* __restrict__ abs_sum,
                                              float* __restrict__ q) {
  __shared__ float sk[256];
  int t = threadIdx.x;
  int j = blockIdx.x * 256 + t;
  float sj = s[j];
  float acc = 0.f;
  for (int c = 0; c < Dd; c += 256) {
    __syncthreads();
    sk[t] = s[c + t];
    __syncthreads();
#pragma unroll 16
    for (int k = 0; k < 256; k += 4) {
      float4 sv = *(const float4*)&sk[k];   // broadcast b128 reads
      acc += fabsf(sj - sv.x) + fabsf(sj - sv.y) + fabsf(sj - sv.z) + fabsf(sj - sv.w);
    }
  }
  abs_sum[j] = acc;
  float v = 2048.0f * sj;
  float p = __expf(-acc);
  float4 q0, q1, q2, q3;
  q0.x = p;                              // t=0
  p *= v;                q0.y = p;       // t=1
  p *= v * 0.5f;         q0.z = p;       // t=2
  p *= v * (1.f / 3.f);  q0.w = p;       // t=3
  p *= v * 0.25f;        q1.x = p;       // t=4
  p *= v * 0.2f;         q1.y = p;       // t=5
  p *= v * (1.f / 6.f);  q1.z = p;       // t=6
  p *= v * (1.f / 7.f);  q1.w = p;       // t=7
  p *= v * 0.125f;       q2.x = p;       // t=8
  p *= v * (1.f / 9.f);  q2.y = p;       // t=9
  p *= v * 0.1f;         q2.z = p;       // t=10
  p *= v * (1.f / 11.f); q2.w = p;       // t=11
  q3.x = 0.f; q3.y = 0.f; q3.z = 0.f; q3.w = 0.f;   // padding t=12..15
  float4* qv = (float4*)&q[(size_t)j * TP];
  qv[0] = q0; qv[1] = q1; qv[2] = q2; qv[3] = q3;
}

// K2: per d: Z_d (wave reduction), then coeff[d][t] = u_d^t / Z_d (padded 16).
__global__ __launch_bounds__(256) void k_wd(const float* __restrict__ s,
                                            const float* __restrict__ abs_sum,
                                            float* __restrict__ coeff) {
  int w = threadIdx.x >> 6, l = threadIdx.x & 63;
  int d = blockIdx.x * 4 + w;
  float scal = 2047.0f - 2.0f * (float)d;
  float sum = 0.f;
#pragma unroll
  for (int it = 0; it < 32; ++it) {
    int j = it * 64 + l;
    sum += __expf(fmaf(scal, s[j], -abs_sum[j]));
  }
#pragma unroll
  for (int off = 32; off > 0; off >>= 1) sum += __shfl_xor(sum, off, 64);
  float wd = 1.0f / sum;
  float u = scal * (1.0f / 2048.0f);
  if (l < TP) {
    float p = (l < TU) ? wd : 0.f;
    for (int k = 0; k < l; ++k) p *= u;   // tiny divergent loop, <=15 iters
    coeff[(size_t)d * TP + l] = p;
  }
}

// K3: moment partials. Yp[ch][b][t][f] = sum_{d in chunk} coeff[d][t]*x[b][d][f].
// One block = one (b, chunk); 256 threads x float2 = full 512-f row per load
// (2048 B coalesced per wave-quad). LDS-broadcast coeff: 3 x b128 per row.
__global__ __launch_bounds__(256) void k_mom(const float* __restrict__ x,
                                             const float* __restrict__ coeff,
                                             float* __restrict__ Yp) {
  __shared__ float cf[DC * TP];  // 4 KB
  int t = threadIdx.x;
  int b = blockIdx.x;
  int ch = blockIdx.y;
  *(float4*)&cf[t * 4] = *(const float4*)&coeff[(size_t)ch * DC * TP + t * 4];
  __syncthreads();

  const float* xb = x + ((size_t)b * Dd + (size_t)ch * DC) * Ff + 2 * t;
  float2 acc[TU];
#pragma unroll
  for (int tt = 0; tt < TU; ++tt) acc[tt] = make_float2(0.f, 0.f);

#pragma unroll 8
  for (int d = 0; d < DC; ++d) {
    float2 xv = *(const float2*)&xb[(size_t)d * Ff];
    const float4* cp = (const float4*)&cf[d * TP];  // same addr all lanes: broadcast
    float cfr[TU];
    *(float4*)&cfr[0] = cp[0];
    *(float4*)&cfr[4] = cp[1];
    *(float4*)&cfr[8] = cp[2];
#pragma unroll
    for (int tt = 0; tt < TU; ++tt) {
      acc[tt].x = fmaf(cfr[tt], xv.x, acc[tt].x);
      acc[tt].y = fmaf(cfr[tt], xv.y, acc[tt].y);
    }
  }

  float* yp = Yp + ((size_t)(ch * Bsz + b) * TU) * Ff + 2 * t;
#pragma unroll
  for (int tt = 0; tt < TU; ++tt)
    *(float2*)&yp[(size_t)tt * Ff] = acc[tt];
}

// K3b: reduce partials over chunks: Y[b][t][f] = sum_ch Yp[ch][b][t][f].
// Yp slabs are fresh in L2/L3 -> mostly cache reads.
__global__ __launch_bounds__(256) void k_red(const float* __restrict__ Yp,
                                             float* __restrict__ Y) {
  int i = (blockIdx.x * 256 + threadIdx.x) * 4;  // over B*TU*F = 196608 floats
  float4 a = make_float4(0.f, 0.f, 0.f, 0.f);
#pragma unroll
  for (int c = 0; c < NC; ++c) {
    float4 v = *(const float4*)&Yp[(size_t)c * (Bsz * TU * Ff) + i];
    a.x += v.x; a.y += v.y; a.z += v.z; a.w += v.w;
  }
  *(float4*)&Y[i] = a;
}

// K4: out[b][j][f] = sum_t q[j][t] * Y[b][t][f].
// r1/r7 structure: one block = (b, 64-row j-tile); Y slice in registers
// (float2), q in LDS (3 x b128 broadcast per j); float2 stores.
__global__ __launch_bounds__(256) void k_out(const float* __restrict__ Y,
                                             const float* __restrict__ q,
                                             float* __restrict__ out) {
  __shared__ float qs[64 * TP];  // 4 KB
  int t = threadIdx.x;
  int b = blockIdx.x;
  int j0 = blockIdx.y * 64;
  *(float4*)&qs[t * 4] = *(const float4*)&q[(size_t)j0 * TP + t * 4];
  __syncthreads();

  const float* yb = Y + (size_t)b * TU * Ff + 2 * t;
  float2 y[TU];
#pragma unroll
  for (int tt = 0; tt < TU; ++tt) y[tt] = *(const float2*)&yb[(size_t)tt * Ff];

  float* ob = out + ((size_t)b * Dd + j0) * Ff + 2 * t;
  for (int j = 0; j < 64; ++j) {
    const float4* qp = (const float4*)&qs[j * TP];  // broadcast
    float qr[TU];
    *(float4*)&qr[0] = qp[0];
    *(float4*)&qr[4] = qp[1];
    *(float4*)&qr[8] = qp[2];
    // two-way split to halve the fma dependency chain
    float ox0 = 0.f, ox1 = 0.f, oy0 = 0.f, oy1 = 0.f;
#pragma unroll
    for (int tt = 0; tt < TU; tt += 2) {
      ox0 = fmaf(qr[tt], y[tt].x, ox0);
      oy0 = fmaf(qr[tt], y[tt].y, oy0);
      ox1 = fmaf(qr[tt + 1], y[tt + 1].x, ox1);
      oy1 = fmaf(qr[tt + 1], y[tt + 1].y, oy1);
    }
    *(float2*)&ob[(size_t)j * Ff] = make_float2(ox0 + ox1, oy0 + oy1);
  }
}

extern "C" void kernel_launch(void* const* d_in, const int* in_sizes, int n_in,
                              void* d_out, int out_size, void* d_ws, size_t ws_size,
                              hipStream_t stream) {
  const float* x = (const float*)d_in[0];
  const float* s = (const float*)d_in[1];
  float* out = (float*)d_out;

  char* ws = (char*)d_ws;
  float* abs_sum = (float*)ws;                            // 8 KB
  float* q = (float*)(ws + 8192);                         // 128 KB
  float* coeff = (float*)(ws + 8192 + 131072);            // 128 KB
  float* Y = (float*)(ws + 270336);                       // 768 KB (32*12*512*4)
  float* Yp = (float*)(ws + 270336 + 786432);             // 25.2 MB

  k_prep<<<Dd / 256, 256, 0, stream>>>(s, abs_sum, q);
  k_wd<<<Dd / 4, 256, 0, stream>>>(s, abs_sum, coeff);
  k_mom<<<dim3(Bsz, NC), 256, 0, stream>>>(x, coeff, Yp);
  k_red<<<(Bsz * TU * Ff) / (256 * 4), 256, 0, stream>>>(Yp, Y);
  k_out<<<dim3(Bsz, Dd / 64), 256, 0, stream>>>(Y, q, out);
}